// Round 2
// baseline (299625.391 us; speedup 1.0000x reference)
//
#include <hip/hip_runtime.h>
#include <cstddef>
#include <cstdint>
#include <cmath>

#define NBLK 256
#define NTHR 512

// ws float offsets
#define WS_WT    64
#define WS_EMB   262208
#define WS_CTX   270400
#define WS_HDN   303168
#define WS_VV    335936
#define WS_SC    368704
#define WS_PS    499776
#define WS_PACC  500032

__device__ __forceinline__ float dot4(float4 a, float4 b) {
    return a.x*b.x + a.y*b.y + a.z*b.z + a.w*b.w;
}

// device-scope grid barrier (gen/sense based). All NBLK blocks must call.
__device__ __forceinline__ void gridbar(unsigned* cnt, unsigned* gen) {
    __syncthreads();
    if (threadIdx.x == 0) {
        unsigned g = __atomic_load_n(gen, __ATOMIC_RELAXED);
        __threadfence();   // release: make this block's phase writes visible
        unsigned prev = __atomic_fetch_add(cnt, 1u, __ATOMIC_ACQ_REL);
        if (prev == NBLK - 1u) {
            __atomic_store_n(cnt, 0u, __ATOMIC_RELAXED);
            __threadfence();
            __atomic_store_n(gen, g + 1u, __ATOMIC_RELEASE);
        } else {
            while (__atomic_load_n(gen, __ATOMIC_ACQUIRE) == g)
                __builtin_amdgcn_s_sleep(1);
        }
        __threadfence();   // acquire: invalidate stale L1/L2 before proceeding
    }
    __syncthreads();
}

__global__ __launch_bounds__(NTHR, 2) void nmt_fused(
    const float* __restrict__ enc, const int* __restrict__ mask,
    const float* __restrict__ embTab, const float* __restrict__ Wih,
    const float* __restrict__ bih, const float* __restrict__ bhh,
    const float* __restrict__ Wa, const float* __restrict__ Wout,
    const float* __restrict__ bout, float* __restrict__ out,
    float* __restrict__ ws)
{
    __shared__ float smem[32 * 512];     // 64 KiB

    const int blk = blockIdx.x;
    const int tid = threadIdx.x;

    unsigned* cnt = (unsigned*)ws;
    unsigned* gen = (unsigned*)ws + 32;
    float* WT   = ws + WS_WT;
    float* emb  = ws + WS_EMB;
    float* ctx  = ws + WS_CTX;
    float* hdn  = ws + WS_HDN;
    float* vv   = ws + WS_VV;
    float* sc   = ws + WS_SC;
    float* ps   = ws + WS_PS;    // [64][4] (3 used)
    float* pacc = ws + WS_PACC;  // [64][3][512]

    // ---------------- prologue ----------------
    if (blk < 64) {
        const int b = blk;
        int* ism = (int*)smem;
        ism[tid] = mask[b * 512 + tid];
        __syncthreads();
        for (int off = 256; off; off >>= 1) {
            if (tid < off) ism[tid] += ism[tid + off];
            __syncthreads();
        }
        int tl = ism[0] - 1;
        if (tl < 0) tl = 0;
        pacc[(b * 3 + 0) * 512 + tid] = enc[((size_t)(b * 512 + tl)) * 512 + tid];
        pacc[(b * 3 + 1) * 512 + tid] = 0.f;
        pacc[(b * 3 + 2) * 512 + tid] = 0.f;
        if (tid < 4) ps[b * 4 + tid] = (tid == 0) ? 1.f : 0.f;
        if (tid < 128) emb[b * 128 + tid] = 0.f;
    } else if (blk < 128) {
        const int j = blk - 64;   // k-slab of 8
        for (int k2 = 0; k2 < 8; ++k2) {
            const int kk = j * 8 + k2;
            WT[(size_t)tid * 512 + kk] = Wa[(size_t)kk * 512 + tid];
        }
    }
    gridbar(cnt, gen);

    // ---------------- main loop ----------------
    for (int t = 0; t < 512; ++t) {
        // ===== P1: gates GEMM (i,g,o; f dead) + ctx materialize + LSTM =====
        {
            const int bg = blk >> 6, cg = blk & 63;
            const int bb = tid >> 5, q = tid & 31;
            const int b = bg * 16 + bb;

            // materialize ctx for P2 (this block's 16b x 8col patch)
            if (tid < 128) {
                const int b2 = bg * 16 + (tid >> 3);
                const int col = cg * 8 + (tid & 7);
                float s2 = ps[b2 * 4] + ps[b2 * 4 + 1] + ps[b2 * 4 + 2];
                float inv2 = (s2 != 0.f) ? 1.f / s2 : 0.f;
                float a = pacc[(b2 * 3 + 0) * 512 + col]
                        + pacc[(b2 * 3 + 1) * 512 + col]
                        + pacc[(b2 * 3 + 2) * 512 + col];
                ctx[b2 * 512 + col] = a * inv2;
            }

            const float s_all = ps[b * 4] + ps[b * 4 + 1] + ps[b * 4 + 2];
            const float inv = (s_all != 0.f) ? 1.f / s_all : 0.f;

            // x = [emb | ctx(=Σparts*inv) | enc_t] in registers, 36 floats
            float4 x[9];
            x[0] = *(const float4*)(emb + b * 128 + q * 4);
            #pragma unroll
            for (int c = 1; c <= 4; ++c) {
                const int k2 = (c - 1) * 128 + q * 4;
                float4 p0 = *(const float4*)(pacc + (b * 3 + 0) * 512 + k2);
                float4 p1 = *(const float4*)(pacc + (b * 3 + 1) * 512 + k2);
                float4 p2 = *(const float4*)(pacc + (b * 3 + 2) * 512 + k2);
                x[c].x = (p0.x + p1.x + p2.x) * inv;
                x[c].y = (p0.y + p1.y + p2.y) * inv;
                x[c].z = (p0.z + p1.z + p2.z) * inv;
                x[c].w = (p0.w + p1.w + p2.w) * inv;
            }
            const float* encb = enc + ((size_t)(b * 512 + t)) * 512;
            #pragma unroll
            for (int c = 5; c <= 8; ++c)
                x[c] = *(const float4*)(encb + (c - 5) * 128 + q * 4);

            float acc[24];
            #pragma unroll
            for (int rr = 0; rr < 24; ++rr) acc[rr] = 0.f;

            #pragma unroll
            for (int gate = 0; gate < 3; ++gate) {
                const int goff = (gate == 0) ? 0 : ((gate == 1) ? 1024 : 1536);
                #pragma unroll
                for (int cc = 0; cc < 8; ++cc) {
                    const float* wr = Wih + (size_t)(goff + cg * 8 + cc) * 1152 + q * 4;
                    float a = 0.f;
                    #pragma unroll
                    for (int c = 0; c < 9; ++c) {
                        float4 w = *(const float4*)(wr + c * 128);
                        a += dot4(w, x[c]);
                    }
                    acc[gate * 8 + cc] = a;
                }
            }
            #pragma unroll
            for (int rr = 0; rr < 24; ++rr) {
                #pragma unroll
                for (int off = 1; off < 32; off <<= 1)
                    acc[rr] += __shfl_xor(acc[rr], off);
            }
            if (q == 0) {
                #pragma unroll
                for (int cc = 0; cc < 8; ++cc) {
                    const int col = cg * 8 + cc;
                    float ig = acc[cc]      + bih[col]        + bhh[col];
                    float gg = acc[8 + cc]  + bih[1024 + col] + bhh[1024 + col];
                    float og = acc[16 + cc] + bih[1536 + col] + bhh[1536 + col];
                    float cv = (1.f / (1.f + expf(-ig))) * tanhf(gg);
                    float hv = (1.f / (1.f + expf(-og))) * tanhf(cv);
                    hdn[b * 512 + col] = hv;
                }
            }
        }
        gridbar(cnt, gen);

        // ===== P2: scores = [hdn|ctx] @ Wout^T + bout ; v = WT @ hdn =====
        {
            const int bg = blk >> 6, vg = blk & 63;
            const int bb = tid >> 5, q = tid & 31;
            const int b = bg * 16 + bb;

            float4 x[8];
            #pragma unroll
            for (int c = 0; c < 4; ++c)
                x[c] = *(const float4*)(hdn + b * 512 + c * 128 + q * 4);
            #pragma unroll
            for (int c = 4; c < 8; ++c)
                x[c] = *(const float4*)(ctx + b * 512 + (c - 4) * 128 + q * 4);

            float acc[32];
            #pragma unroll
            for (int cc = 0; cc < 32; ++cc) {
                const float* wr = Wout + (size_t)(vg * 32 + cc) * 1024 + q * 4;
                float a = 0.f;
                #pragma unroll
                for (int c = 0; c < 8; ++c) {
                    float4 w = *(const float4*)(wr + c * 128);
                    a += dot4(w, x[c]);
                }
                acc[cc] = a;
            }
            #pragma unroll
            for (int cc = 0; cc < 32; ++cc) {
                #pragma unroll
                for (int off = 1; off < 32; off <<= 1)
                    acc[cc] += __shfl_xor(acc[cc], off);
            }
            if (q == 0) {
                #pragma unroll
                for (int cc = 0; cc < 32; ++cc)
                    sc[b * 2048 + vg * 32 + cc] = acc[cc] + bout[vg * 32 + cc];
            }

            float acc2[8];
            #pragma unroll
            for (int cc = 0; cc < 8; ++cc) {
                const float* wr = WT + (size_t)(vg * 8 + cc) * 512 + q * 4;
                float a = 0.f;
                #pragma unroll
                for (int c = 0; c < 4; ++c) {
                    float4 w = *(const float4*)(wr + c * 128);
                    a += dot4(w, x[c]);
                }
                acc2[cc] = a;
            }
            #pragma unroll
            for (int cc = 0; cc < 8; ++cc) {
                #pragma unroll
                for (int off = 1; off < 32; off <<= 1)
                    acc2[cc] += __shfl_xor(acc2[cc], off);
            }
            if (q == 0) {
                #pragma unroll
                for (int cc = 0; cc < 8; ++cc)
                    vv[b * 512 + vg * 8 + cc] = acc2[cc];
            }
        }
        gridbar(cnt, gen);

        // ===== P3: flash partials (192 blocks) | argmax/logp/emb (64) =====
        {
            if (blk < 192) {
                const int b = blk / 3, r = blk % 3;
                const int start = r * 171;
                const int cnt_r = (r < 2) ? 171 : 170;
                const int lane = tid & 63, w = tid >> 6;
                const int l = lane & 15, g = lane >> 4;

                float4 v4[8];
                #pragma unroll
                for (int j = 0; j < 8; ++j)
                    v4[j] = *(const float4*)(vv + b * 512 + l * 32 + j * 4);

                float4 a4[8];
                #pragma unroll
                for (int j = 0; j < 8; ++j) a4[j] = make_float4(0.f, 0.f, 0.f, 0.f);
                float s_loc = 0.f;

                for (int p = 0; p < 6; ++p) {
                    const int rr = p * 32 + w * 4 + g;
                    const bool valid = rr < cnt_r;
                    const int rc = valid ? rr : (cnt_r - 1);
                    const int ta = start + rc;
                    const int mk = mask[b * 512 + ta];
                    const float* er = enc + ((size_t)(b * 512 + ta)) * 512 + l * 32;
                    float4 e4[8];
                    #pragma unroll
                    for (int j = 0; j < 8; ++j)
                        e4[j] = *(const float4*)(er + j * 4);
                    float d = 0.f;
                    #pragma unroll
                    for (int j = 0; j < 8; ++j) d += dot4(e4[j], v4[j]);
                    d += __shfl_xor(d, 1);
                    d += __shfl_xor(d, 2);
                    d += __shfl_xor(d, 4);
                    d += __shfl_xor(d, 8);
                    const float pw = (valid && mk) ? expf(d) : 0.f;
                    s_loc += pw;
                    #pragma unroll
                    for (int j = 0; j < 8; ++j) {
                        a4[j].x += pw * e4[j].x; a4[j].y += pw * e4[j].y;
                        a4[j].z += pw * e4[j].z; a4[j].w += pw * e4[j].w;
                    }
                }
                // write 32 acc-sets, j-rotated by l to spread LDS banks
                {
                    float* row = smem + (w * 4 + g) * 512 + l * 32;
                    #pragma unroll
                    for (int j = 0; j < 8; ++j)
                        ((float4*)row)[(j + l) & 7] = a4[j];
                }
                __syncthreads();
                {
                    const int lh = tid >> 5, jh = (tid >> 2) & 7, comp = tid & 3;
                    const int off0 = lh * 32 + ((jh + lh) & 7) * 4 + comp;
                    float a = 0.f;
                    #pragma unroll
                    for (int R = 0; R < 32; ++R) a += smem[R * 512 + off0];
                    pacc[(b * 3 + r) * 512 + tid] = a;
                }
                __syncthreads();
                if (l == 0) smem[w * 4 + g] = s_loc;
                __syncthreads();
                if (tid == 0) {
                    float s = 0.f;
                    #pragma unroll
                    for (int R = 0; R < 32; ++R) s += smem[R];
                    ps[b * 4 + r] = s;
                }
            } else {
                const int b = blk - 192;
                const float* sb = sc + b * 2048;
                float sv[4];
                float bv = -3.4e38f; int bi = 0;
                #pragma unroll
                for (int jj = 0; jj < 4; ++jj) {
                    const int c = tid + jj * 512;
                    sv[jj] = sb[c];
                    if (sv[jj] > bv) { bv = sv[jj]; bi = c; }
                }
                float* red = smem;
                int* idx = (int*)(smem + 512);
                red[tid] = bv; idx[tid] = bi;
                __syncthreads();
                for (int off = 256; off; off >>= 1) {
                    if (tid < off) {
                        float ov = red[tid + off]; int oi = idx[tid + off];
                        if (ov > red[tid] || (ov == red[tid] && oi < idx[tid])) {
                            red[tid] = ov; idx[tid] = oi;
                        }
                    }
                    __syncthreads();
                }
                const float gmax = red[0];
                const int amax = idx[0];
                __syncthreads();
                float psum = 0.f;
                #pragma unroll
                for (int jj = 0; jj < 4; ++jj) psum += expf(sv[jj] - gmax);
                red[tid] = psum;
                __syncthreads();
                for (int off = 256; off; off >>= 1) {
                    if (tid < off) red[tid] += red[tid + off];
                    __syncthreads();
                }
                const float lse = gmax + logf(red[0]);
                float* ob = out + ((size_t)(b * 512 + t)) * 2048;
                #pragma unroll
                for (int jj = 0; jj < 4; ++jj)
                    ob[tid + jj * 512] = sv[jj] - lse;
                if (tid < 128)
                    emb[b * 128 + tid] = embTab[(size_t)amax * 128 + tid];
            }
        }
        gridbar(cnt, gen);
    }
}

extern "C" void kernel_launch(void* const* d_in, const int* in_sizes, int n_in,
                              void* d_out, int out_size, void* d_ws, size_t ws_size,
                              hipStream_t stream)
{
    const float* enc    = (const float*)d_in[0];
    const int*   mask   = (const int*)  d_in[1];
    const float* embTab = (const float*)d_in[2];
    const float* Wih    = (const float*)d_in[3];
    const float* bih    = (const float*)d_in[4];
    const float* bhh    = (const float*)d_in[5];
    const float* Wa     = (const float*)d_in[6];
    // d_in[7] = b_attn: cancelled by softmax (constant over t)
    const float* Wout   = (const float*)d_in[8];
    const float* bout   = (const float*)d_in[9];
    float* out = (float*)d_out;
    float* wsf = (float*)d_ws;

    // zero the grid-barrier state (ws is poisoned, not re-zeroed, by harness)
    hipMemsetAsync(d_ws, 0, 256, stream);

    void* args[] = {
        (void*)&enc, (void*)&mask, (void*)&embTab, (void*)&Wih, (void*)&bih,
        (void*)&bhh, (void*)&Wa, (void*)&Wout, (void*)&bout, (void*)&out,
        (void*)&wsf
    };
    hipLaunchCooperativeKernel((void*)nmt_fused, dim3(NBLK), dim3(NTHR),
                               args, 0, stream);
}

// Round 3
// 193499.158 us; speedup vs baseline: 1.5485x; 1.5485x over previous
//
#include <hip/hip_runtime.h>
#include <cstddef>
#include <cstdint>
#include <cmath>

#define NBLK 256
#define NTHR 512

// ws float offsets
#define WS_WT    64        // [512][512] W_attn^T
#define WS_CTX   262208    // [64][512]
#define WS_HDN   294976    // [64][512]
#define WS_VV    327744    // [64][512]
#define WS_SC    360512    // [64][2048]
#define WS_PART  491584    // [64][64][4] {max, sumexp, idxf, pad}
#define WS_PACC  507968    // [64][4][512]
#define WS_PS    639040    // [64][4]
#define WS_EMB   639296    // [64][128]
// total 647488 floats = 2.59 MB

__device__ __forceinline__ float dot4(float4 a, float4 b) {
    return a.x*b.x + a.y*b.y + a.z*b.z + a.w*b.w;
}

// ---- agent-coherent (sc1) accesses: no cache maintenance, LLC-coherent ----
__device__ __forceinline__ float ld1(const float* p) {
    return __hip_atomic_load(p, __ATOMIC_RELAXED, __HIP_MEMORY_SCOPE_AGENT);
}
__device__ __forceinline__ void st1(float* p, float v) {
    __hip_atomic_store(p, v, __ATOMIC_RELAXED, __HIP_MEMORY_SCOPE_AGENT);
}
__device__ __forceinline__ float2 ld2(const float* p) {
    unsigned long long u = __hip_atomic_load((unsigned long long*)p,
        __ATOMIC_RELAXED, __HIP_MEMORY_SCOPE_AGENT);
    union { unsigned long long u; float2 f; } c; c.u = u; return c.f;
}
__device__ __forceinline__ void st2(float* p, float a, float b) {
    union { unsigned long long u; float2 f; } c; c.f = make_float2(a, b);
    __hip_atomic_store((unsigned long long*)p, c.u,
        __ATOMIC_RELAXED, __HIP_MEMORY_SCOPE_AGENT);
}

// Relaxed grid barrier: monotonic counter, no fences, no per-spin cache ops.
// Every thread drains its own vmem stores (sc1 stores complete = visible at
// agent scope) before thread0 arrives.
__device__ __forceinline__ void gridbar(unsigned* cnt, unsigned* gen, unsigned iter) {
    asm volatile("s_waitcnt vmcnt(0) lgkmcnt(0)" ::: "memory");
    __syncthreads();
    if (threadIdx.x == 0) {
        unsigned prev = __hip_atomic_fetch_add(cnt, 1u, __ATOMIC_RELAXED,
                                               __HIP_MEMORY_SCOPE_AGENT);
        if (prev == iter * NBLK - 1u) {
            __hip_atomic_store(gen, iter, __ATOMIC_RELAXED, __HIP_MEMORY_SCOPE_AGENT);
        } else {
            while (__hip_atomic_load(gen, __ATOMIC_RELAXED, __HIP_MEMORY_SCOPE_AGENT) < iter)
                __builtin_amdgcn_s_sleep(2);
        }
    }
    __syncthreads();
    asm volatile("" ::: "memory");
}

__global__ __launch_bounds__(NTHR, 2) void nmt_fused(
    const float* __restrict__ enc, const int* __restrict__ mask,
    const float* __restrict__ embTab, const float* __restrict__ Wih,
    const float* __restrict__ bih, const float* __restrict__ bhh,
    const float* __restrict__ Wa, const float* __restrict__ Wout,
    const float* __restrict__ bout, float* __restrict__ out,
    float* __restrict__ ws)
{
    __shared__ float smem[16384];   // 64 KiB

    const int blk = blockIdx.x;
    const int tid = threadIdx.x;

    unsigned* cnt = (unsigned*)ws;
    unsigned* gen = (unsigned*)ws + 32;
    float* WT   = ws + WS_WT;
    float* ctx  = ws + WS_CTX;
    float* hdn  = ws + WS_HDN;
    float* vv   = ws + WS_VV;
    float* sc   = ws + WS_SC;
    float* part = ws + WS_PART;
    float* pacc = ws + WS_PACC;
    float* ps   = ws + WS_PS;
    float* embw = ws + WS_EMB;

    unsigned bar = 0;

    // ---------------- prologue ----------------
    if (blk < 64) {
        const int b = blk;
        int* ism = (int*)smem;
        ism[tid] = mask[b * 512 + tid];
        __syncthreads();
        for (int off = 256; off; off >>= 1) {
            if (tid < off) ism[tid] += ism[tid + off];
            __syncthreads();
        }
        int tl = ism[0] - 1;
        if (tl < 0) tl = 0;
        st1(pacc + ((b * 4 + 0) << 9) + tid, enc[((size_t)(b * 512 + tl)) * 512 + tid]);
        st1(pacc + ((b * 4 + 1) << 9) + tid, 0.f);
        st1(pacc + ((b * 4 + 2) << 9) + tid, 0.f);
        st1(pacc + ((b * 4 + 3) << 9) + tid, 0.f);
        if (tid < 4) st1(ps + b * 4 + tid, (tid == 0) ? 1.f : 0.f);
        if (tid < 128) st1(embw + b * 128 + tid, 0.f);
    } else if (blk < 128) {
        const int j = blk - 64;     // 8-row slab of Wa
        for (int k2 = 0; k2 < 8; ++k2) {
            const int kk = j * 8 + k2;
            st1(WT + (size_t)tid * 512 + kk, Wa[(size_t)kk * 512 + tid]);
        }
    }
    gridbar(cnt, gen, ++bar);

    // ---------------- main loop ----------------
    for (int t = 0; t < 512; ++t) {
        // ===== P1: gates GEMM (i,g,o; f dead) + LSTM -> hdn; ctx write =====
        {
            const int bg = blk >> 6, cg = blk & 63;
            const int b = tid >> 5, q = tid & 31;
            const int bb = bg * 16 + b;
            const int col0 = cg * 8;

            float2 s01 = ld2(ps + bb * 4);
            float2 s23 = ld2(ps + bb * 4 + 2);
            float s_all = s01.x + s01.y + s23.x + s23.y;
            float inv = (s_all != 0.f) ? 1.f / s_all : 0.f;

            float4 x[9];
            {
                float2 e0 = ld2(embw + bb * 128 + q * 4);
                float2 e1 = ld2(embw + bb * 128 + q * 4 + 2);
                x[0] = make_float4(e0.x, e0.y, e1.x, e1.y);
            }
            #pragma unroll
            for (int c = 1; c <= 4; ++c) {
                const int k2 = (c - 1) * 128 + q * 4;
                float ax = 0.f, ay = 0.f, az = 0.f, aw = 0.f;
                #pragma unroll
                for (int r = 0; r < 4; ++r) {
                    const float* pp = pacc + ((bb * 4 + r) << 9) + k2;
                    float2 p0 = ld2(pp), p1 = ld2(pp + 2);
                    ax += p0.x; ay += p0.y; az += p1.x; aw += p1.y;
                }
                x[c] = make_float4(ax * inv, ay * inv, az * inv, aw * inv);
                if (cg == 0) {      // one writer per bg-group
                    st2(ctx + bb * 512 + k2,     x[c].x, x[c].y);
                    st2(ctx + bb * 512 + k2 + 2, x[c].z, x[c].w);
                }
            }
            const float* encb = enc + ((size_t)(bb * 512 + t)) * 512;
            #pragma unroll
            for (int c = 5; c <= 8; ++c)
                x[c] = *(const float4*)(encb + (c - 5) * 128 + q * 4);

            float acc[24];
            #pragma unroll
            for (int rr = 0; rr < 24; ++rr) acc[rr] = 0.f;
            #pragma unroll
            for (int gate = 0; gate < 3; ++gate) {
                const int goff = (gate == 0) ? 0 : ((gate == 1) ? 1024 : 1536);
                #pragma unroll
                for (int cc = 0; cc < 8; ++cc) {
                    const float* wr = Wih + (size_t)(goff + col0 + cc) * 1152 + q * 4;
                    float a = 0.f;
                    #pragma unroll
                    for (int c = 0; c < 9; ++c)
                        a += dot4(*(const float4*)(wr + c * 128), x[c]);
                    acc[gate * 8 + cc] = a;
                }
            }
            #pragma unroll
            for (int rr = 0; rr < 24; ++rr) {
                #pragma unroll
                for (int off = 1; off < 32; off <<= 1)
                    acc[rr] += __shfl_xor(acc[rr], off);
            }
            if (q == 0) {
                float hv[8];
                #pragma unroll
                for (int cc = 0; cc < 8; ++cc) {
                    const int col = col0 + cc;
                    float ig = acc[cc]      + bih[col]        + bhh[col];
                    float gg = acc[8 + cc]  + bih[1024 + col] + bhh[1024 + col];
                    float og = acc[16 + cc] + bih[1536 + col] + bhh[1536 + col];
                    float cv = (1.f / (1.f + expf(-ig))) * tanhf(gg);
                    hv[cc] = (1.f / (1.f + expf(-og))) * tanhf(cv);
                }
                #pragma unroll
                for (int i = 0; i < 4; ++i)
                    st2(hdn + bb * 512 + col0 + 2 * i, hv[2 * i], hv[2 * i + 1]);
            }
        }
        gridbar(cnt, gen, ++bar);

        // ===== P2: scores (+bias, partial max/lse) + vv, fused x-pass =====
        {
            const int bg = blk >> 6, vg = blk & 63;
            const int b = tid >> 5, q = tid & 31;
            const int bb = bg * 16 + b;
            const int c0 = vg * 32;

            float4 x[8];
            #pragma unroll
            for (int j = 0; j < 8; ++j) {
                const int k = q * 4 + j * 128;
                const float* src = (j < 4) ? (hdn + bb * 512 + k)
                                           : (ctx + bb * 512 + (k - 512));
                float2 p0 = ld2(src), p1 = ld2(src + 2);
                x[j] = make_float4(p0.x, p0.y, p1.x, p1.y);
            }

            float acc[32];
            #pragma unroll
            for (int cc = 0; cc < 32; ++cc) {
                const float* wr = Wout + (size_t)(c0 + cc) * 1024 + q * 4;
                float a = 0.f;
                #pragma unroll
                for (int j = 0; j < 8; ++j)
                    a += dot4(*(const float4*)(wr + j * 128), x[j]);
                acc[cc] = a;
            }
            float acc2[8];
            #pragma unroll
            for (int cc = 0; cc < 8; ++cc) {
                const float* wr = WT + (size_t)(vg * 8 + cc) * 512 + q * 4;
                float a = 0.f;
                #pragma unroll
                for (int j = 0; j < 4; ++j)
                    a += dot4(*(const float4*)(wr + j * 128), x[j]);
                acc2[cc] = a;
            }
            #pragma unroll
            for (int cc = 0; cc < 32; ++cc) {
                #pragma unroll
                for (int off = 1; off < 32; off <<= 1)
                    acc[cc] += __shfl_xor(acc[cc], off);
            }
            #pragma unroll
            for (int cc = 0; cc < 8; ++cc) {
                #pragma unroll
                for (int off = 1; off < 32; off <<= 1)
                    acc2[cc] += __shfl_xor(acc2[cc], off);
            }
            if (q == 0) {
                float lmax = -3.4e38f; int lidx = 0;
                #pragma unroll
                for (int cc = 0; cc < 32; ++cc) {
                    acc[cc] += bout[c0 + cc];
                    if (acc[cc] > lmax) { lmax = acc[cc]; lidx = c0 + cc; }
                }
                float se = 0.f;
                #pragma unroll
                for (int cc = 0; cc < 32; ++cc) se += expf(acc[cc] - lmax);
                #pragma unroll
                for (int i = 0; i < 16; ++i)
                    st2(sc + bb * 2048 + c0 + 2 * i, acc[2 * i], acc[2 * i + 1]);
                st2(part + (bb * 64 + vg) * 4,     lmax, se);
                st2(part + (bb * 64 + vg) * 4 + 2, (float)lidx, 0.f);
                #pragma unroll
                for (int i = 0; i < 4; ++i)
                    st2(vv + bb * 512 + vg * 8 + 2 * i, acc2[2 * i], acc2[2 * i + 1]);
            }
        }
        gridbar(cnt, gen, ++bar);

        // ===== P3: lse/argmax combine + logp write + emb + flash =====
        {
            const int fb = blk >> 2, r = blk & 3;
            // stage vv[fb] into LDS
            if (tid < 256) {
                float2 v = ld2(vv + fb * 512 + tid * 2);
                smem[tid * 2] = v.x; smem[tid * 2 + 1] = v.y;
            }
            // combine 64 score-partials for fb (one wave)
            if (tid < 64) {
                const float* pp = part + (fb * 64 + tid) * 4;
                float2 a = ld2(pp);
                float2 ci = ld2(pp + 2);
                float m = a.x, se = a.y; int idx = (int)ci.x;
                #pragma unroll
                for (int off = 1; off < 64; off <<= 1) {
                    float mo  = __shfl_xor(m, off);
                    float seo = __shfl_xor(se, off);
                    int   io  = __shfl_xor(idx, off);
                    float M = fmaxf(m, mo);
                    se = se * expf(m - M) + seo * expf(mo - M);
                    idx = (mo > m || (mo == m && io < idx)) ? io : idx;
                    m = M;
                }
                if (tid == 0) { smem[16380] = m + logf(se); smem[16381] = (float)idx; }
            }
            __syncthreads();
            const float lse = smem[16380];
            const int amax = (int)smem[16381];

            const int w = tid >> 6, lane = tid & 63, l = lane & 15, g = lane >> 4;
            float4 v4[8];
            #pragma unroll
            for (int j = 0; j < 8; ++j)
                v4[j] = *(const float4*)(smem + l * 32 + j * 4);

            // logp output row for step t (this block's 512 cols)
            {
                const int col = r * 512 + tid;
                float v = ld1(sc + fb * 2048 + col) - lse;
                out[((size_t)fb * 512 + t) * 2048 + col] = v;
            }
            // greedy embedding feed for t+1
            if (r == 0 && tid < 64) {
                const float* er = embTab + (size_t)amax * 128 + tid * 2;
                st2(embw + fb * 128 + tid * 2, er[0], er[1]);
            }

            // flash partial over rows [r*128, r*128+128)
            float4 a4[8];
            #pragma unroll
            for (int j = 0; j < 8; ++j) a4[j] = make_float4(0.f, 0.f, 0.f, 0.f);
            float s_loc = 0.f;
            for (int p = 0; p < 4; ++p) {
                const int ta = r * 128 + p * 32 + w * 4 + g;
                const int mk = mask[fb * 512 + ta];
                const float* er = enc + ((size_t)(fb * 512 + ta)) * 512 + l * 32;
                float4 e4[8];
                #pragma unroll
                for (int j = 0; j < 8; ++j) e4[j] = *(const float4*)(er + j * 4);
                float d = 0.f;
                #pragma unroll
                for (int j = 0; j < 8; ++j) d += dot4(e4[j], v4[j]);
                d += __shfl_xor(d, 1);
                d += __shfl_xor(d, 2);
                d += __shfl_xor(d, 4);
                d += __shfl_xor(d, 8);
                const float pw = mk ? expf(d) : 0.f;
                s_loc += pw;
                #pragma unroll
                for (int j = 0; j < 8; ++j) {
                    a4[j].x += pw * e4[j].x; a4[j].y += pw * e4[j].y;
                    a4[j].z += pw * e4[j].z; a4[j].w += pw * e4[j].w;
                }
            }
            __syncthreads();   // vv/lse region dead; reuse full smem
            {
                float* row = smem + (w * 4 + g) * 512 + l * 32;
                #pragma unroll
                for (int j = 0; j < 8; ++j)
                    ((float4*)row)[(j + l) & 7] = a4[j];
            }
            __syncthreads();
            {
                const int lh = tid >> 5, jh = (tid >> 2) & 7, comp = tid & 3;
                const int off0 = lh * 32 + ((jh + lh) & 7) * 4 + comp;
                float a = 0.f;
                #pragma unroll
                for (int R = 0; R < 32; ++R) a += smem[R * 512 + off0];
                st1(pacc + ((fb * 4 + r) << 9) + tid, a);
            }
            __syncthreads();
            if (l == 0) smem[w * 4 + g] = s_loc;
            __syncthreads();
            if (tid == 0) {
                float s = 0.f;
                #pragma unroll
                for (int R = 0; R < 32; ++R) s += smem[R];
                st1(ps + fb * 4 + r, s);
            }
        }
        gridbar(cnt, gen, ++bar);
    }
}

extern "C" void kernel_launch(void* const* d_in, const int* in_sizes, int n_in,
                              void* d_out, int out_size, void* d_ws, size_t ws_size,
                              hipStream_t stream)
{
    const float* enc    = (const float*)d_in[0];
    const int*   mask   = (const int*)  d_in[1];
    const float* embTab = (const float*)d_in[2];
    const float* Wih    = (const float*)d_in[3];
    const float* bih    = (const float*)d_in[4];
    const float* bhh    = (const float*)d_in[5];
    const float* Wa     = (const float*)d_in[6];
    // d_in[7] = b_attn: cancelled by softmax (constant over t)
    const float* Wout   = (const float*)d_in[8];
    const float* bout   = (const float*)d_in[9];
    float* out = (float*)d_out;
    float* wsf = (float*)d_ws;

    // zero barrier state (cnt monotonic within one launch; reset per launch)
    hipMemsetAsync(d_ws, 0, 256, stream);

    void* args[] = {
        (void*)&enc, (void*)&mask, (void*)&embTab, (void*)&Wih, (void*)&bih,
        (void*)&bhh, (void*)&Wa, (void*)&Wout, (void*)&bout, (void*)&out,
        (void*)&wsf
    };
    hipLaunchCooperativeKernel((void*)nmt_fused, dim3(NBLK), dim3(NTHR),
                               args, 0, stream);
}

// Round 4
// 47946.753 us; speedup vs baseline: 6.2491x; 4.0357x over previous
//
#include <hip/hip_runtime.h>
#include <cstddef>
#include <cstdint>
#include <cmath>

#define NBLK 256
#define NTHR 512

// ---- dynamic LDS float offsets (33024 floats = 129 KiB) ----
#define L_WIH   0        // [6][1152]  gate rows i0,i1,g0,g1,o0,o1 for cols 2k,2k+1
#define L_WOUT  6912     // [8][1024]  score rows 8k..8k+7
#define L_WT    15104    // [2][512]   W_attn^T rows 2k,2k+1
#define L_VVS   16128    // [512]      staged vv[b]
#define L_FA    16640    // [16384]    flash/reduce scratch
#define L_TOT   33024

// ---- ws float offsets ----
#define WS_HDN   64       // [64][512]
#define WS_VV    32832    // [64][512]
#define WS_SC    65600    // [64][2048]
#define WS_PACC  196672   // [2][64][512]
#define WS_PS    262208   // [2][64]
#define WS_EMB   262336   // [64][128]

__device__ __forceinline__ float dot4(float4 a, float4 b) {
    return a.x*b.x + a.y*b.y + a.z*b.z + a.w*b.w;
}

// sc1 (agent-scope) stores: write-through to the coherence point (MALL).
__device__ __forceinline__ void st1(float* p, float v) {
    __hip_atomic_store(p, v, __ATOMIC_RELAXED, __HIP_MEMORY_SCOPE_AGENT);
}
__device__ __forceinline__ void st2(float* p, float a, float b) {
    union { unsigned long long u; float2 f; } c; c.f = make_float2(a, b);
    __hip_atomic_store((unsigned long long*)p, c.u,
        __ATOMIC_RELAXED, __HIP_MEMORY_SCOPE_AGENT);
}

// Grid barrier: relaxed monotonic counter + relaxed spin (R3-proven), then a
// per-wave agent-scope ACQUIRE load -> compiler emits the L1/L2 invalidate
// that makes subsequent PLAIN cached loads coherent with sc1 stores.
__device__ __forceinline__ void gridbar(unsigned* cnt, unsigned* gen, unsigned iter) {
    asm volatile("s_waitcnt vmcnt(0) lgkmcnt(0)" ::: "memory");
    __syncthreads();
    if (threadIdx.x == 0) {
        unsigned prev = __hip_atomic_fetch_add(cnt, 1u, __ATOMIC_RELAXED,
                                               __HIP_MEMORY_SCOPE_AGENT);
        if (prev == iter * NBLK - 1u) {
            __hip_atomic_store(gen, iter, __ATOMIC_RELAXED, __HIP_MEMORY_SCOPE_AGENT);
        } else {
            while (__hip_atomic_load(gen, __ATOMIC_RELAXED, __HIP_MEMORY_SCOPE_AGENT) < iter)
                __builtin_amdgcn_s_sleep(2);
        }
    }
    __syncthreads();
    (void)__hip_atomic_load(gen, __ATOMIC_ACQUIRE, __HIP_MEMORY_SCOPE_AGENT);
    asm volatile("" ::: "memory");
}

__global__ __launch_bounds__(NTHR, 1) void nmt_fused(
    const float* __restrict__ enc, const int* __restrict__ mask,
    const float* __restrict__ embTab, const float* __restrict__ Wih,
    const float* __restrict__ bih, const float* __restrict__ bhh,
    const float* __restrict__ Wa, const float* __restrict__ Wout,
    const float* __restrict__ bout, float* __restrict__ out,
    float* __restrict__ ws)
{
    extern __shared__ float smem[];

    const int blk = blockIdx.x;
    const int tid = threadIdx.x;

    unsigned* cnt = (unsigned*)ws;
    unsigned* gen = (unsigned*)ws + 32;
    float* hdnw = ws + WS_HDN;
    float* vvw  = ws + WS_VV;
    float* scw  = ws + WS_SC;
    float* pacc = ws + WS_PACC;
    float* ps   = ws + WS_PS;
    float* embw = ws + WS_EMB;

    unsigned bar = 0;

    // ---------------- prologue: weights -> LDS (resident all 512 steps) ----
    {
        #pragma unroll
        for (int s = 0; s < 6; ++s) {
            const int grow = (s < 2) ? (2 * blk + s)
                           : (s < 4) ? (1024 + 2 * blk + (s - 2))
                                     : (1536 + 2 * blk + (s - 4));
            for (int off = tid; off < 1152; off += NTHR)
                smem[L_WIH + s * 1152 + off] = Wih[(size_t)grow * 1152 + off];
        }
        #pragma unroll
        for (int s = 0; s < 8; ++s)
            for (int off = tid; off < 1024; off += NTHR)
                smem[L_WOUT + s * 1024 + off] = Wout[(size_t)(8 * blk + s) * 1024 + off];
        #pragma unroll
        for (int s = 0; s < 2; ++s)
            smem[L_WT + s * 512 + tid] = Wa[(size_t)tid * 512 + (2 * blk + s)];
    }
    // per-block constant biases -> registers (uniform -> SGPRs)
    const int c0 = 2 * blk;
    const float bi0 = bih[c0]        + bhh[c0];
    const float bi1 = bih[c0 + 1]    + bhh[c0 + 1];
    const float bg0 = bih[1024 + c0] + bhh[1024 + c0];
    const float bg1 = bih[1025 + c0] + bhh[1025 + c0];
    const float bo0 = bih[1536 + c0] + bhh[1536 + c0];
    const float bo1 = bih[1537 + c0] + bhh[1537 + c0];
    float bo[8];
    #pragma unroll
    for (int s = 0; s < 8; ++s) bo[s] = bout[8 * blk + s];

    // state init (blocks 0..63): ctx0 -> pacc slot1, ps slot1=1, emb=0
    if (blk < 64) {
        const int b = blk;
        int* ism = (int*)(smem + L_FA);
        ism[tid] = mask[b * 512 + tid];
        __syncthreads();
        for (int off = 256; off; off >>= 1) {
            if (tid < off) ism[tid] += ism[tid + off];
            __syncthreads();
        }
        int tl = ism[0] - 1;
        if (tl < 0) tl = 0;
        st1(pacc + 32768 + b * 512 + tid, enc[((size_t)(b * 512 + tl)) * 512 + tid]);
        if (tid == 0) st1(ps + 64 + b, 1.f);
        if (tid < 128) st1(embw + b * 128 + tid, 0.f);
    }
    gridbar(cnt, gen, ++bar);

    // ---------------- main loop ----------------
    for (int t = 0; t < 512; ++t) {
        const int cur = t & 1;
        float* paccC = pacc + cur * 32768;
        const float* paccP = pacc + (cur ^ 1) * 32768;
        float* psC = ps + cur * 64;
        const float* psP = ps + (cur ^ 1) * 64;

        // ===== P1: gates GEMM from LDS weights + LSTM -> hdn =====
        {
            // zero cur-slot accumulators for P3's atomics
            if (tid < 128) st1(paccC + blk * 128 + tid, 0.f);
            if (blk == 0 && tid < 64) st1(psC + tid, 0.f);

            const int q = tid & 15, bl = tid >> 4;
            #pragma unroll
            for (int pass = 0; pass < 2; ++pass) {
                const int b = pass * 32 + bl;
                float sden = psP[b];
                float inv = (sden != 0.f) ? 1.f / sden : 0.f;

                float4 x[18];
                const float* embb = embw + b * 128;
                x[0] = *(const float4*)(embb + q * 8);
                x[1] = *(const float4*)(embb + q * 8 + 4);
                const float* pb = paccP + b * 512;
                #pragma unroll
                for (int c = 0; c < 4; ++c) {
                    float4 p0 = *(const float4*)(pb + c * 128 + q * 8);
                    float4 p1 = *(const float4*)(pb + c * 128 + q * 8 + 4);
                    x[2 + c * 2] = make_float4(p0.x * inv, p0.y * inv, p0.z * inv, p0.w * inv);
                    x[3 + c * 2] = make_float4(p1.x * inv, p1.y * inv, p1.z * inv, p1.w * inv);
                }
                const float* eb = enc + ((size_t)(b * 512 + t)) * 512;
                #pragma unroll
                for (int c = 0; c < 4; ++c) {
                    x[10 + c * 2] = *(const float4*)(eb + c * 128 + q * 8);
                    x[11 + c * 2] = *(const float4*)(eb + c * 128 + q * 8 + 4);
                }

                float acc[6];
                #pragma unroll
                for (int s = 0; s < 6; ++s) {
                    const float* wl = smem + L_WIH + s * 1152 + q * 8;
                    float a = 0.f;
                    #pragma unroll
                    for (int c = 0; c < 9; ++c) {
                        a += dot4(*(const float4*)(wl + c * 128),     x[c * 2]);
                        a += dot4(*(const float4*)(wl + c * 128 + 4), x[c * 2 + 1]);
                    }
                    acc[s] = a;
                }
                #pragma unroll
                for (int s = 0; s < 6; ++s) {
                    #pragma unroll
                    for (int off = 1; off < 16; off <<= 1)
                        acc[s] += __shfl_xor(acc[s], off);
                }
                if (q == 0) {
                    float ig0 = acc[0] + bi0, ig1 = acc[1] + bi1;
                    float gg0 = acc[2] + bg0, gg1 = acc[3] + bg1;
                    float og0 = acc[4] + bo0, og1 = acc[5] + bo1;
                    float cv0 = (1.f / (1.f + expf(-ig0))) * tanhf(gg0);
                    float cv1 = (1.f / (1.f + expf(-ig1))) * tanhf(gg1);
                    float h0 = (1.f / (1.f + expf(-og0))) * tanhf(cv0);
                    float h1 = (1.f / (1.f + expf(-og1))) * tanhf(cv1);
                    st2(hdnw + b * 512 + c0, h0, h1);
                }
            }
        }
        gridbar(cnt, gen, ++bar);

        // ===== P2: scores (8 rows) + vv (2 cols) from LDS weights =====
        {
            const int q = tid & 15, bl = tid >> 4;
            #pragma unroll
            for (int pass = 0; pass < 2; ++pass) {
                const int b = pass * 32 + bl;
                float sden = psP[b];
                float inv = (sden != 0.f) ? 1.f / sden : 0.f;

                float4 x[16];
                const float* hb = hdnw + b * 512;
                #pragma unroll
                for (int c = 0; c < 4; ++c) {
                    x[c * 2]     = *(const float4*)(hb + c * 128 + q * 8);
                    x[c * 2 + 1] = *(const float4*)(hb + c * 128 + q * 8 + 4);
                }
                const float* pb = paccP + b * 512;
                #pragma unroll
                for (int c = 0; c < 4; ++c) {
                    float4 p0 = *(const float4*)(pb + c * 128 + q * 8);
                    float4 p1 = *(const float4*)(pb + c * 128 + q * 8 + 4);
                    x[8 + c * 2] = make_float4(p0.x * inv, p0.y * inv, p0.z * inv, p0.w * inv);
                    x[9 + c * 2] = make_float4(p1.x * inv, p1.y * inv, p1.z * inv, p1.w * inv);
                }

                float acc[8];
                #pragma unroll
                for (int s = 0; s < 8; ++s) {
                    const float* wl = smem + L_WOUT + s * 1024 + q * 8;
                    float a = 0.f;
                    #pragma unroll
                    for (int c = 0; c < 8; ++c) {
                        a += dot4(*(const float4*)(wl + c * 128),     x[c * 2]);
                        a += dot4(*(const float4*)(wl + c * 128 + 4), x[c * 2 + 1]);
                    }
                    acc[s] = a;
                }
                float av[2];
                #pragma unroll
                for (int s = 0; s < 2; ++s) {
                    const float* wl = smem + L_WT + s * 512 + q * 8;
                    float a = 0.f;
                    #pragma unroll
                    for (int c = 0; c < 4; ++c) {
                        a += dot4(*(const float4*)(wl + c * 128),     x[c * 2]);
                        a += dot4(*(const float4*)(wl + c * 128 + 4), x[c * 2 + 1]);
                    }
                    av[s] = a;
                }
                #pragma unroll
                for (int s = 0; s < 8; ++s) {
                    #pragma unroll
                    for (int off = 1; off < 16; off <<= 1)
                        acc[s] += __shfl_xor(acc[s], off);
                }
                #pragma unroll
                for (int s = 0; s < 2; ++s) {
                    #pragma unroll
                    for (int off = 1; off < 16; off <<= 1)
                        av[s] += __shfl_xor(av[s], off);
                }
                if (q == 0) {
                    float sv0 = acc[0] + bo[0], sv1 = acc[1] + bo[1];
                    float sv2 = acc[2] + bo[2], sv3 = acc[3] + bo[3];
                    float sv4 = acc[4] + bo[4], sv5 = acc[5] + bo[5];
                    float sv6 = acc[6] + bo[6], sv7 = acc[7] + bo[7];
                    float* sb = scw + b * 2048 + 8 * blk;
                    st2(sb,     sv0, sv1);
                    st2(sb + 2, sv2, sv3);
                    st2(sb + 4, sv4, sv5);
                    st2(sb + 6, sv6, sv7);
                    st2(vvw + b * 512 + c0, av[0], av[1]);
                }
            }
        }
        gridbar(cnt, gen, ++bar);

        // ===== P3: lse/argmax + logp + emb + flash attention partial =====
        {
            const int fb = blk >> 2, r = blk & 3;
            float* fa = smem + L_FA;
            int* fai = (int*)(fa + 512);

            // stage vv[fb] into LDS
            if (tid < 256) {
                float2 v = *(const float2*)(vvw + fb * 512 + tid * 2);
                *(float2*)(smem + L_VVS + tid * 2) = v;
            }

            // block-redundant lse/argmax over sc[fb]
            const float* sb = scw + fb * 2048;
            float sv[4];
            float bv = -3.4e38f; int bi = 0;
            #pragma unroll
            for (int jj = 0; jj < 4; ++jj) {
                const int c = tid + (jj << 9);
                sv[jj] = sb[c];
                if (sv[jj] > bv) { bv = sv[jj]; bi = c; }
            }
            fa[tid] = bv; fai[tid] = bi;
            __syncthreads();
            for (int off = 256; off; off >>= 1) {
                if (tid < off) {
                    float ov = fa[tid + off]; int oi = fai[tid + off];
                    if (ov > fa[tid] || (ov == fa[tid] && oi < fai[tid])) {
                        fa[tid] = ov; fai[tid] = oi;
                    }
                }
                __syncthreads();
            }
            const float gmax = fa[0];
            const int amax = fai[0];
            __syncthreads();
            float psum = 0.f;
            #pragma unroll
            for (int jj = 0; jj < 4; ++jj) psum += expf(sv[jj] - gmax);
            fa[tid] = psum;
            __syncthreads();
            for (int off = 256; off; off >>= 1) {
                if (tid < off) fa[tid] += fa[tid + off];
                __syncthreads();
            }
            const float lse = gmax + logf(fa[0]);

            // logp quarter for this block
            {
                float v = ((r == 0) ? sv[0] : (r == 1) ? sv[1] : (r == 2) ? sv[2] : sv[3]) - lse;
                st1(out + ((size_t)(fb * 512 + t)) * 2048 + r * 512 + tid, v);
            }
            // greedy embedding feed for t+1
            if (r == 0 && tid < 64) {
                const float* er = embTab + (size_t)amax * 128 + tid * 2;
                st2(embw + fb * 128 + tid * 2, er[0], er[1]);
            }

            // flash partial over rows [r*128, r*128+128)
            const int w = tid >> 6, lane = tid & 63, l = lane & 15, g = lane >> 4;
            float4 v4[8];
            #pragma unroll
            for (int j = 0; j < 8; ++j)
                v4[j] = *(const float4*)(smem + L_VVS + l * 32 + j * 4);

            float4 a4[8];
            #pragma unroll
            for (int j = 0; j < 8; ++j) a4[j] = make_float4(0.f, 0.f, 0.f, 0.f);
            float s_loc = 0.f;
            for (int p = 0; p < 4; ++p) {
                const int ta = r * 128 + p * 32 + w * 4 + g;
                const int mk = mask[fb * 512 + ta];
                const float* er = enc + ((size_t)(fb * 512 + ta)) * 512 + l * 32;
                float4 e4[8];
                #pragma unroll
                for (int j = 0; j < 8; ++j) e4[j] = *(const float4*)(er + j * 4);
                float d = 0.f;
                #pragma unroll
                for (int j = 0; j < 8; ++j) d += dot4(e4[j], v4[j]);
                d += __shfl_xor(d, 1);
                d += __shfl_xor(d, 2);
                d += __shfl_xor(d, 4);
                d += __shfl_xor(d, 8);
                const float pw = mk ? expf(d) : 0.f;
                s_loc += pw;
                #pragma unroll
                for (int j = 0; j < 8; ++j) {
                    a4[j].x += pw * e4[j].x; a4[j].y += pw * e4[j].y;
                    a4[j].z += pw * e4[j].z; a4[j].w += pw * e4[j].w;
                }
            }
            __syncthreads();   // scratch region dead; reuse
            {
                float* row = fa + (w * 4 + g) * 512 + l * 32;
                #pragma unroll
                for (int j = 0; j < 8; ++j)
                    ((float4*)row)[(j + l) & 7] = a4[j];
            }
            __syncthreads();
            {
                const int lh = tid >> 5, jh = (tid >> 2) & 7, comp = tid & 3;
                const int off0 = lh * 32 + ((jh + lh) & 7) * 4 + comp;
                float a = 0.f;
                #pragma unroll
                for (int R = 0; R < 32; ++R) a += fa[R * 512 + off0];
                atomicAdd(paccC + fb * 512 + tid, a);
            }
            __syncthreads();
            if (l == 0) fa[w * 4 + g] = s_loc;
            __syncthreads();
            if (tid == 0) {
                float s = 0.f;
                #pragma unroll
                for (int R = 0; R < 32; ++R) s += fa[R];
                atomicAdd(psC + fb, s);
            }
        }
        gridbar(cnt, gen, ++bar);
    }
}

extern "C" void kernel_launch(void* const* d_in, const int* in_sizes, int n_in,
                              void* d_out, int out_size, void* d_ws, size_t ws_size,
                              hipStream_t stream)
{
    const float* enc    = (const float*)d_in[0];
    const int*   mask   = (const int*)  d_in[1];
    const float* embTab = (const float*)d_in[2];
    const float* Wih    = (const float*)d_in[3];
    const float* bih    = (const float*)d_in[4];
    const float* bhh    = (const float*)d_in[5];
    const float* Wa     = (const float*)d_in[6];
    // d_in[7] = b_attn: cancelled by softmax (constant over t)
    const float* Wout   = (const float*)d_in[8];
    const float* bout   = (const float*)d_in[9];
    float* out = (float*)d_out;
    float* wsf = (float*)d_ws;

    // allow 129 KiB dynamic LDS (idempotent; ignore error by design)
    (void)hipFuncSetAttribute((const void*)nmt_fused,
                              hipFuncAttributeMaxDynamicSharedMemorySize, 163840);

    // zero barrier state (cnt/gen)
    hipMemsetAsync(d_ws, 0, 256, stream);

    void* args[] = {
        (void*)&enc, (void*)&mask, (void*)&embTab, (void*)&Wih, (void*)&bih,
        (void*)&bhh, (void*)&Wa, (void*)&Wout, (void*)&bout, (void*)&out,
        (void*)&wsf
    };
    hipLaunchCooperativeKernel((void*)nmt_fused, dim3(NBLK), dim3(NTHR),
                               args, (unsigned)(L_TOT * sizeof(float)), stream);
}